// Round 8
// baseline (294.141 us; speedup 1.0000x reference)
//
#include <hip/hip_runtime.h>
#include <math.h>

// entmax-1.5 rows of 4096 x 32000 f32.
// Persistent blocks (grid=256, 1024 thr), 16 rows/block, depth-2 register
// pipeline, asm-pinned loads. Round-8: wave-UNIFORM VMEM counts.
//   ROWV4=8000 is not a multiple of 1024, so waves 13-15 used to skip their
//   8th store -> their vmcnt FIFO was off by one and vmcnt(16) left 1 load
//   of the next buffer unretired (round-7 absmax 0.85). Now stores clamp the
//   index to 0 exactly like loads (the clamped lanes hold the transform of
//   row elements 0..3, so the duplicate store writes the identical value
//   thread 0 writes). Every wave: exactly 8 loads + 8 stores per row.
// Order per row: stats+tau (barriers) -> o[8] = transform (kept live) ->
// prefetch loads -> stores from o -> vmcnt(16). Keeping o live across the
// prefetch stops regalloc from reusing store-data regs as load dests (the
// round-5/6 hidden protective vmcnt that serialized the store drain).
// Steady-state FIFO at wait_vm16: [other-buf loads(8) | prefetch(8) |
// stores(8)] -> retires exactly the buffer processed next.
// tau solved in wave 0 over candidates {x > xmax-2} (tau* in [-1,0] on the
// z=(x-xmax)/2 scale => candidate set is a superset of the support).

#define ROWLEN 32000
#define ROWV4  8000
#define BLOCK  1024
#define NV4    8              // 8 float4 per thread
#define NW     16             // waves per block
#define CAND_MAX 4096
#define GRID   256

typedef float f32x4 __attribute__((ext_vector_type(4)));

__device__ __forceinline__ void wg_barrier() {
  // LDS-visibility barrier that does NOT drain vmcnt (prefetch stays live).
  asm volatile("s_waitcnt lgkmcnt(0)" ::: "memory");
  __builtin_amdgcn_sched_barrier(0);
  __builtin_amdgcn_s_barrier();
  __builtin_amdgcn_sched_barrier(0);
}

__device__ __forceinline__ void wait_vm8() {
  asm volatile("s_waitcnt vmcnt(8)" ::: "memory");
  __builtin_amdgcn_sched_barrier(0);   // rule #18
}
__device__ __forceinline__ void wait_vm16() {
  asm volatile("s_waitcnt vmcnt(16)" ::: "memory");
  __builtin_amdgcn_sched_barrier(0);   // rule #18
}

__device__ __forceinline__ void issue_row(f32x4 (&v)[NV4],
                                          const float* __restrict__ rowp,
                                          int t) {
#pragma unroll
  for (int i = 0; i < NV4; ++i) {
    int idx = i * BLOCK + t;
    idx = idx < ROWV4 ? idx : 0;           // clamp: OOB lanes reload elem 0
    const float* p = rowp + (size_t)idx * 4;
    asm volatile("global_load_dwordx4 %0, %1, off"
                 : "=&v"(v[i]) : "v"(p) : "memory");
  }
}

__global__ __launch_bounds__(BLOCK)
void entmax15_kernel(const float* __restrict__ x, float* __restrict__ out,
                     int rows, int rpb) {
  const int t    = threadIdx.x;
  const int lane = t & 63;
  const int wid  = t >> 6;

  __shared__ float s_max[NW];
  __shared__ int   s_total;
  __shared__ float s_tau;
  __shared__ float s_cand[CAND_MAX];

  const int rbeg = blockIdx.x * rpb;
  const int rend = min(rbeg + rpb, rows);
  if (rbeg >= rend) return;

  f32x4 A[NV4], B[NV4];

  // ---- stats + tau solve: returns cc with p = max(x*0.5 - cc, 0)^2 ----
  auto stats = [&](f32x4 (&v)[NV4]) -> float {
    if (t == 0) s_total = 0;

    float lmax = -1e30f;
#pragma unroll
    for (int i = 0; i < NV4; ++i) {
      int idx = i * BLOCK + t;
      if (idx < ROWV4)
        lmax = fmaxf(lmax,
                     fmaxf(fmaxf(v[i].x, v[i].y), fmaxf(v[i].z, v[i].w)));
    }
#pragma unroll
    for (int m = 32; m >= 1; m >>= 1) lmax = fmaxf(lmax, __shfl_xor(lmax, m));
    if (lane == 0) s_max[wid] = lmax;
    wg_barrier();                         // #1 (covers s_total=0)
    float xmax = s_max[0];
#pragma unroll
    for (int w = 1; w < NW; ++w) xmax = fmaxf(xmax, s_max[w]);
    const float thr = xmax - 2.0f;        // z > -1  <=>  x > xmax-2

    int c = 0;
#pragma unroll
    for (int i = 0; i < NV4; ++i) {
      int idx = i * BLOCK + t;
      if (idx < ROWV4)
        c += (v[i].x > thr) + (v[i].y > thr) + (v[i].z > thr) + (v[i].w > thr);
    }
    int incl = c;
#pragma unroll
    for (int m = 1; m < 64; m <<= 1) {
      int nb = __shfl_up(incl, m);
      if (lane >= m) incl += nb;
    }
    int wbase = 0;
    if (lane == 63) wbase = atomicAdd(&s_total, incl);
    wbase = __shfl(wbase, 63);
    {
      int off = wbase + incl - c;
#pragma unroll
      for (int i = 0; i < NV4; ++i) {
        int idx = i * BLOCK + t;
        if (idx < ROWV4) {
          float a;
          a = v[i].x; if (a > thr) { if (off < CAND_MAX) s_cand[off] = (a - xmax) * 0.5f; ++off; }
          a = v[i].y; if (a > thr) { if (off < CAND_MAX) s_cand[off] = (a - xmax) * 0.5f; ++off; }
          a = v[i].z; if (a > thr) { if (off < CAND_MAX) s_cand[off] = (a - xmax) * 0.5f; ++off; }
          a = v[i].w; if (a > thr) { if (off < CAND_MAX) s_cand[off] = (a - xmax) * 0.5f; ++off; }
        }
      }
    }
    wg_barrier();                         // #2: candidates + total final
    const int total = min(s_total, CAND_MAX);  // tail beyond is ~e^-26

    if (wid == 0) {
      float tau = -1.0f;
      const int ng = (total + 511) >> 9;  // groups of 8 x 64 lanes
      for (int it = 0; it < 6; ++it) {    // Newton, monotone from the left
        float s = 0.f, q = 0.f;
        for (int g = 0; g < ng; ++g) {
#pragma unroll
          for (int k = 0; k < 8; ++k) {
            int j = lane + ((g << 3) + k) * 64;
            float z = s_cand[j & (CAND_MAX - 1)];
            float d = z - tau;
            if (j < total && d > 0.f) { s += d; q += d * d; }
          }
        }
#pragma unroll
        for (int m = 32; m >= 1; m >>= 1) {
          s += __shfl_xor(s, m);
          q += __shfl_xor(q, m);
        }
        if (s > 0.f) tau += (q - 1.0f) / (2.0f * s);
      }
      for (int it = 0; it < 2; ++it) {    // closed-form support fix-point
        float kk = 0.f, s1 = 0.f, s2 = 0.f;
        for (int g = 0; g < ng; ++g) {
#pragma unroll
          for (int k = 0; k < 8; ++k) {
            int j = lane + ((g << 3) + k) * 64;
            float z = s_cand[j & (CAND_MAX - 1)];
            if (j < total && z > tau) { kk += 1.f; s1 += z; s2 += z * z; }
          }
        }
#pragma unroll
        for (int m = 32; m >= 1; m >>= 1) {
          kk += __shfl_xor(kk, m);
          s1 += __shfl_xor(s1, m);
          s2 += __shfl_xor(s2, m);
        }
        float disc = s1 * s1 - kk * (s2 - 1.0f);
        tau = (s1 - sqrtf(fmaxf(disc, 0.f))) / kk;
      }
      if (lane == 0) s_tau = tau;
    }
    wg_barrier();                         // #3: tau ready
    return fmaf(xmax, 0.5f, s_tau);       // p = max(x*0.5 - cc, 0)^2
  };

  // ---- transform into o[] (kept live), THEN prefetch, THEN store ----
  // Stores clamp idx to 0 like loads: OOB lanes hold the transform of row
  // elements 0..3 (they loaded the clamped address), so the duplicate store
  // writes the identical value thread 0 writes. 8 stores per thread, always.
  auto finish = [&](f32x4 (&v)[NV4], float cc, int row, int nextrow) {
    f32x4 o[NV4];
#pragma unroll
    for (int i = 0; i < NV4; ++i) {
      float d;
      d = fmaf(v[i].x, 0.5f, -cc); o[i].x = d > 0.f ? d * d : 0.f;
      d = fmaf(v[i].y, 0.5f, -cc); o[i].y = d > 0.f ? d * d : 0.f;
      d = fmaf(v[i].z, 0.5f, -cc); o[i].z = d > 0.f ? d * d : 0.f;
      d = fmaf(v[i].w, 0.5f, -cc); o[i].w = d > 0.f ? d * d : 0.f;
    }
    issue_row(v, x + (size_t)nextrow * ROWLEN, t);   // o live across this
    f32x4* __restrict__ outr = (f32x4*)(out + (size_t)row * ROWLEN);
#pragma unroll
    for (int i = 0; i < NV4; ++i) {
      int idx = i * BLOCK + t;
      idx = idx < ROWV4 ? idx : 0;         // uniform VMEM count (benign dup)
      outr[idx] = o[i];
    }
  };

  // ---- depth-2 pipeline ----
  issue_row(A, x + (size_t)rbeg * ROWLEN, t);
  {
    int rB0 = (rbeg + 1 < rend) ? rbeg + 1 : rbeg;
    issue_row(B, x + (size_t)rB0 * ROWLEN, t);
  }
  wait_vm8();                              // A ready (B in flight)
  for (int r = rbeg; r < rend; r += 2) {
    float cc = stats(A);
    finish(A, cc, r, (r + 2 < rend) ? r + 2 : rend - 1);
    wait_vm16();                           // B-loads retired; stores+prefetch live
    if (r + 1 >= rend) break;
    cc = stats(B);
    finish(B, cc, r + 1, (r + 3 < rend) ? r + 3 : rend - 1);
    wait_vm16();                           // A-loads retired
  }
}

extern "C" void kernel_launch(void* const* d_in, const int* in_sizes, int n_in,
                              void* d_out, int out_size, void* d_ws, size_t ws_size,
                              hipStream_t stream) {
  const float* x = (const float*)d_in[0];
  float* out = (float*)d_out;
  int rows = in_sizes[0] / ROWLEN;
  int grid = rows < GRID ? rows : GRID;
  int rpb  = (rows + grid - 1) / grid;
  hipLaunchKernelGGL(entmax15_kernel, dim3(grid), dim3(BLOCK), 0, stream,
                     x, out, rows, rpb);
}

// Round 10
// 253.645 us; speedup vs baseline: 1.1597x; 1.1597x over previous
//
#include <hip/hip_runtime.h>
#include <math.h>

// entmax-1.5 rows of 4096 x 32000 f32.
// Round-10: round-6 kernel VERBATIM, only GRID 256 -> 512 (rpb 8).
// NO __launch_bounds__ min-waves coercion: round 9 proved forcing VGPR<=64
// makes the compiler spill to scratch, and scratch buffer-ops count in the
// per-wave vmcnt FIFO -> the hand-counted vmcnt(16) retired spill traffic
// instead of prefetch loads (absmax 20992). Round 6/8 compile NATURALLY to
// VGPR=64 with zero spills = exactly the 32-waves/CU boundary, so two
// 16-wave blocks/CU co-reside on their own. Block A's solve/barrier phases
// overlap block B's streaming loads (TLP cover for the serial tau-solve).
// Depth-2 register pipeline, asm-pinned loads, vmcnt(16) waits; stores kept
// newest in the per-wave VMEM FIFO. tau solved in wave 0 over candidates
// {x > xmax-2} (tau* in [-1,0] on z=(x-xmax)/2 scale => superset of support).

#define ROWLEN 32000
#define ROWV4  8000
#define BLOCK  1024
#define NV4    8              // 8 float4 per thread
#define NW     16             // waves per block
#define CAND_MAX 4096
#define GRID   512            // 2 blocks per CU (if VGPR stays 64)

typedef float f32x4 __attribute__((ext_vector_type(4)));

__device__ __forceinline__ void wg_barrier() {
  // LDS-visibility barrier that does NOT drain vmcnt (prefetch stays live).
  asm volatile("s_waitcnt lgkmcnt(0)" ::: "memory");
  __builtin_amdgcn_sched_barrier(0);
  __builtin_amdgcn_s_barrier();
  __builtin_amdgcn_sched_barrier(0);
}

__device__ __forceinline__ void wait_vm8() {
  asm volatile("s_waitcnt vmcnt(8)" ::: "memory");
  __builtin_amdgcn_sched_barrier(0);   // rule #18
}
__device__ __forceinline__ void wait_vm16() {
  asm volatile("s_waitcnt vmcnt(16)" ::: "memory");
  __builtin_amdgcn_sched_barrier(0);   // rule #18
}

__device__ __forceinline__ void issue_row(f32x4 (&v)[NV4],
                                          const float* __restrict__ rowp,
                                          int t) {
#pragma unroll
  for (int i = 0; i < NV4; ++i) {
    int idx = i * BLOCK + t;
    idx = idx < ROWV4 ? idx : 0;           // clamp: OOB lanes reload elem 0
    const float* p = rowp + (size_t)idx * 4;
    asm volatile("global_load_dwordx4 %0, %1, off"
                 : "=&v"(v[i]) : "v"(p) : "memory");
  }
}

__global__ __launch_bounds__(BLOCK)      // NO min-waves arg (round-9 lesson)
void entmax15_kernel(const float* __restrict__ x, float* __restrict__ out,
                     int rows, int rpb) {
  const int t    = threadIdx.x;
  const int lane = t & 63;
  const int wid  = t >> 6;

  __shared__ float s_max[NW];
  __shared__ int   s_total;
  __shared__ float s_tau;
  __shared__ float s_cand[CAND_MAX];

  const int rbeg = blockIdx.x * rpb;
  const int rend = min(rbeg + rpb, rows);
  if (rbeg >= rend) return;

  f32x4 A[NV4], B[NV4];

  // process: stats -> tau -> STORES LAST (stores stay newest in VMEM FIFO)
  auto process = [&](f32x4 (&v)[NV4], int row) {
    if (t == 0) s_total = 0;

    // ---- row max (regs) ----
    float lmax = -1e30f;
#pragma unroll
    for (int i = 0; i < NV4; ++i) {
      int idx = i * BLOCK + t;
      if (idx < ROWV4)
        lmax = fmaxf(lmax,
                     fmaxf(fmaxf(v[i].x, v[i].y), fmaxf(v[i].z, v[i].w)));
    }
#pragma unroll
    for (int m = 32; m >= 1; m >>= 1) lmax = fmaxf(lmax, __shfl_xor(lmax, m));
    if (lane == 0) s_max[wid] = lmax;
    wg_barrier();                         // #1 (covers s_total=0)
    float xmax = s_max[0];
#pragma unroll
    for (int w = 1; w < NW; ++w) xmax = fmaxf(xmax, s_max[w]);
    const float thr = xmax - 2.0f;        // z > -1  <=>  x > xmax-2

    // ---- count + scan + gather candidates (z-scale) to LDS ----
    int c = 0;
#pragma unroll
    for (int i = 0; i < NV4; ++i) {
      int idx = i * BLOCK + t;
      if (idx < ROWV4)
        c += (v[i].x > thr) + (v[i].y > thr) + (v[i].z > thr) + (v[i].w > thr);
    }
    int incl = c;
#pragma unroll
    for (int m = 1; m < 64; m <<= 1) {
      int nb = __shfl_up(incl, m);
      if (lane >= m) incl += nb;
    }
    int wbase = 0;
    if (lane == 63) wbase = atomicAdd(&s_total, incl);
    wbase = __shfl(wbase, 63);
    {
      int off = wbase + incl - c;
#pragma unroll
      for (int i = 0; i < NV4; ++i) {
        int idx = i * BLOCK + t;
        if (idx < ROWV4) {
          float a;
          a = v[i].x; if (a > thr) { if (off < CAND_MAX) s_cand[off] = (a - xmax) * 0.5f; ++off; }
          a = v[i].y; if (a > thr) { if (off < CAND_MAX) s_cand[off] = (a - xmax) * 0.5f; ++off; }
          a = v[i].z; if (a > thr) { if (off < CAND_MAX) s_cand[off] = (a - xmax) * 0.5f; ++off; }
          a = v[i].w; if (a > thr) { if (off < CAND_MAX) s_cand[off] = (a - xmax) * 0.5f; ++off; }
        }
      }
    }
    wg_barrier();                         // #2: candidates + total final
    const int total = min(s_total, CAND_MAX);  // clamp: tail beyond is ~e^-26

    // ---- tau solve in wave 0 only; 8-wide unrolled LDS reads/round ----
    if (wid == 0) {
      float tau = -1.0f;
      const int ng = (total + 511) >> 9;  // groups of 8 x 64 lanes
      for (int it = 0; it < 6; ++it) {    // Newton, monotone from the left
        float s = 0.f, q = 0.f;
        for (int g = 0; g < ng; ++g) {
#pragma unroll
          for (int k = 0; k < 8; ++k) {
            int j = lane + ((g << 3) + k) * 64;
            float z = s_cand[j & (CAND_MAX - 1)];
            float d = z - tau;
            if (j < total && d > 0.f) { s += d; q += d * d; }
          }
        }
#pragma unroll
        for (int m = 32; m >= 1; m >>= 1) {
          s += __shfl_xor(s, m);
          q += __shfl_xor(q, m);
        }
        if (s > 0.f) tau += (q - 1.0f) / (2.0f * s);
      }
      for (int it = 0; it < 2; ++it) {    // closed-form support fix-point
        float kk = 0.f, s1 = 0.f, s2 = 0.f;
        for (int g = 0; g < ng; ++g) {
#pragma unroll
          for (int k = 0; k < 8; ++k) {
            int j = lane + ((g << 3) + k) * 64;
            float z = s_cand[j & (CAND_MAX - 1)];
            if (j < total && z > tau) { kk += 1.f; s1 += z; s2 += z * z; }
          }
        }
#pragma unroll
        for (int m = 32; m >= 1; m >>= 1) {
          kk += __shfl_xor(kk, m);
          s1 += __shfl_xor(s1, m);
          s2 += __shfl_xor(s2, m);
        }
        float disc = s1 * s1 - kk * (s2 - 1.0f);
        tau = (s1 - sqrtf(fmaxf(disc, 0.f))) / kk;
      }
      if (lane == 0) s_tau = tau;
    }
    wg_barrier();                         // #3: tau ready
    const float cc = fmaf(xmax, 0.5f, s_tau);   // d = x*0.5 - cc

    // ---- store p = max(x*0.5 - cc, 0)^2 (plain stores: L2-ack'd) ----
    f32x4* __restrict__ outr = (f32x4*)(out + (size_t)row * ROWLEN);
#pragma unroll
    for (int i = 0; i < NV4; ++i) {
      int idx = i * BLOCK + t;
      if (idx < ROWV4) {
        f32x4 o;
        float d;
        d = fmaf(v[i].x, 0.5f, -cc); o.x = d > 0.f ? d * d : 0.f;
        d = fmaf(v[i].y, 0.5f, -cc); o.y = d > 0.f ? d * d : 0.f;
        d = fmaf(v[i].z, 0.5f, -cc); o.z = d > 0.f ? d * d : 0.f;
        d = fmaf(v[i].w, 0.5f, -cc); o.w = d > 0.f ? d * d : 0.f;
        outr[idx] = o;
      }
    }
  };

  // ---- depth-2 pipeline; stores + prefetch stay outstanding across waits ----
  issue_row(A, x + (size_t)rbeg * ROWLEN, t);
  {
    int rB0 = (rbeg + 1 < rend) ? rbeg + 1 : rbeg;
    issue_row(B, x + (size_t)rB0 * ROWLEN, t);
  }
  wait_vm8();                              // prologue: only 16 loads out
  for (int r = rbeg; r < rend; r += 2) {
    process(A, r);                         // ends with row-r stores (newest)
    {
      int rn = (r + 2 < rend) ? r + 2 : rend - 1;   // clamp keeps FIFO uniform
      issue_row(A, x + (size_t)rn * ROWLEN, t);
    }
    wait_vm16();                           // B-loads retired; stores in flight
    if (r + 1 >= rend) break;
    process(B, r + 1);
    {
      int rn = (r + 3 < rend) ? r + 3 : rend - 1;
      issue_row(B, x + (size_t)rn * ROWLEN, t);
    }
    wait_vm16();                           // A-loads retired; stores in flight
  }
}

extern "C" void kernel_launch(void* const* d_in, const int* in_sizes, int n_in,
                              void* d_out, int out_size, void* d_ws, size_t ws_size,
                              hipStream_t stream) {
  const float* x = (const float*)d_in[0];
  float* out = (float*)d_out;
  int rows = in_sizes[0] / ROWLEN;
  int grid = rows < GRID ? rows : GRID;
  int rpb  = (rows + grid - 1) / grid;
  hipLaunchKernelGGL(entmax15_kernel, dim3(grid), dim3(BLOCK), 0, stream,
                     x, out, rows, rpb);
}